// Round 22
// baseline (162.909 us; speedup 1.0000x reference)
//
#include <hip/hip_runtime.h>
#include <hip/hip_bf16.h>

// Problem geometry
#define N_ROWS 32000   // Q_OUT*Q_IN*NUM_P
#define SB     12      // SCALAR_BASIS
#define FC     720     // FILTER_C
#define FD     2704    // FILTER_DIM
#define OCOLS  2704    // DIM_OUT*DIM_IN
#define OPAD   2816    // padded o (22*128)
#define ANGD   25
#define PDIM   300     // SB * ANGD
#define KST    320     // PDIM padded to 5*64 (main GEMM K)
#define NT     5       // main GEMM K tiles of 64
#define KP     2720    // FD padded to 85*32 (V-GEMM K)
#define NTV    85      // V-GEMM K tiles of 32
#define GPR    (KP/8)  // 340 groups per Gt row

#define NB_G   425     // KST*GPR/256
#define NBV    110     // 5 * 22 V-GEMM tiles
#define NB_X   5000    // N_ROWS*(KST/8)/256

typedef __attribute__((ext_vector_type(8))) short bf16x8;
typedef __attribute__((ext_vector_type(4))) float f32x4;

__device__ __forceinline__ void gload16(const void* g, void* l) {
    __builtin_amdgcn_global_load_lds(
        (const __attribute__((address_space(1))) void*)g,
        (__attribute__((address_space(3))) void*)l, 16, 0, 0);
}

__device__ __forceinline__ void decode_f(int f, int& c, int& j, int& a) {
    if (f < 144)       { c = f;                         j = 0;            a = 0;  }
    else if (f < 960)  { int t = f - 144;  c = 144 + t/3; j = t - (t/3)*3; a = 1;  }
    else if (f < 2000) { int t = f - 960;  c = 416 + t/5; j = t - (t/5)*5; a = 4;  }
    else if (f < 2560) { int t = f - 2000; c = 624 + t/7; j = t - (t/7)*7; a = 9;  }
    else               { int t = f - 2560; c = 704 + t/9; j = t - (t/9)*9; a = 16; }
}

// ---------------------------------------------------------------------------
// Launch 1: build_G only (R20 body). Gt[p][f] = match ? W[s,c]/sqrt12 : 0.
// ---------------------------------------------------------------------------
__global__ __launch_bounds__(256) void prepG(
    const float* __restrict__ W,
    __hip_bfloat16* __restrict__ Gt)
{
    const int g = blockIdx.x * 256 + threadIdx.x;
    if (g >= KST * GPR) return;
    const int p  = g / GPR;
    const int f0 = (g - p * GPR) * 8;
    const int s     = p / ANGD;
    const int alpha = p - s * ANGD;
    const float inv = 0.28867513459481288f;
    alignas(16) __hip_bfloat16 tmp[8];
    #pragma unroll
    for (int u = 0; u < 8; ++u) {
        const int f = f0 + u;
        float v = 0.f;
        if (p < PDIM && f < FD) {
            int c, j, a;
            decode_f(f, c, j, a);
            if (alpha == a + j) v = W[s * FC + c] * inv;
        }
        tmp[u] = __float2bfloat16(v);
    }
    *(bf16x8*)(Gt + (size_t)p * KP + f0) = *(const bf16x8*)tmp;
}

// ---------------------------------------------------------------------------
// Launch 2: fused gemm_V-direct (blocks [0,NBV)) + build_X ([NBV,NBV+NB_X)).
// gemm_V reads TP (f32) DIRECTLY: reg-stage 2x float4 per lane per row,
// cvt -> bf16, ds_write_b128 to the SAME LDS address gload_lds used
// (layout identical by construction: phys chunk c of row r holds logical
// slot c^(r&3)^((r>>2)&3), matching read-side rslot). Removes cvt_M and
// the 15.3 MB TPb round-trip. B (Gt) staging via gload_lds unchanged.
// Visibility: writer's ds_writes drained by its own lgkmcnt(0) at next
// iter's step-1, then barrier; consumption is 2 iters later. A-loads
// drained by cvt use (in-order vmcnt => B gloads drained too).
// ---------------------------------------------------------------------------
__global__ __launch_bounds__(256, 4) void fused_V_X(
    const float* __restrict__ TP,           // (2704, 2704) f32
    const __hip_bfloat16* __restrict__ B,   // Gt: (KST, KP)
    __hip_bfloat16* __restrict__ V,         // (OPAD, KST)
    const float* __restrict__ sk,
    const float* __restrict__ ang,
    __hip_bfloat16* __restrict__ X)
{
    __shared__ __align__(1024) char lds[24576];

    if (blockIdx.x >= NBV) {
        // ---- build_X branch (no LDS use) ----
        const int idx = (blockIdx.x - NBV) * 256 + threadIdx.x;
        if (idx >= N_ROWS * (KST / 8)) return;
        const int n  = idx / (KST / 8);
        const int p0 = (idx - n * (KST / 8)) * 8;
        const float* skn  = sk  + (size_t)n * SB;
        const float* angn = ang + (size_t)n * ANGD;
        alignas(16) __hip_bfloat16 tmp[8];
        #pragma unroll
        for (int u = 0; u < 8; ++u) {
            const int p = p0 + u;
            float v = 0.f;
            if (p < PDIM) {
                const int s = p / ANGD;
                const int a = p - s * ANGD;
                v = skn[s] * angn[a];
            }
            tmp[u] = __float2bfloat16(v);
        }
        *(bf16x8*)(X + (size_t)n * KST + p0) = *(const bf16x8*)tmp;
        return;
    }

    // ---- gemm_V-direct branch ----
    char* const bufA = lds;            // 2 x 8192 B
    char* const bufB = lds + 16384;    // 2 x 4096 B

    const int tid  = threadIdx.x;
    const int wave = tid >> 6;
    const int lane = tid & 63;

    const int id = blockIdx.x;
    const int bn = id % 5;             // 5 col tiles (64 p each)
    const int bm = id / 5;             // 22 row tiles (128 o each)
    const size_t arow0 = (size_t)bm * 128;
    const size_t brow0 = (size_t)bn * 64;

    const int wr = wave >> 1;
    const int wc = wave & 1;

    const int lrow2 = lane >> 2;
    const int slog  = (lane & 3) ^ (lrow2 & 3) ^ ((lane >> 4) & 3);
    const int sslot = slog << 4;

    // A reg-staging constants: lane owns rows o0, o1; logical f-chunk slog
    const int o0 = (int)arow0 + wave * 16 + lrow2;
    const int o1 = o0 + 64;
    const bool ok0 = o0 < OCOLS;
    const bool ok1 = o1 < OCOLS;

    float4 r00, r01, r10, r11;
    auto A_LOAD = [&](int t) {
        const int colf = t * 32 + slog * 8;       // f32 element index
        const float4 z = {0.f, 0.f, 0.f, 0.f};
        r00 = z; r01 = z; r10 = z; r11 = z;
        if (colf < FD) {                          // 8-aligned, FD%8==0
            if (ok0) {
                const float4* p = (const float4*)(TP + (size_t)o0 * FD + colf);
                r00 = p[0]; r01 = p[1];
            }
            if (ok1) {
                const float4* p = (const float4*)(TP + (size_t)o1 * FD + colf);
                r10 = p[0]; r11 = p[1];
            }
        }
    };
    auto A_WRITE = [&](int half) {
        char* const la = bufA + half * 8192;
        alignas(16) __hip_bfloat16 w0[8], w1[8];
        w0[0] = __float2bfloat16(r00.x); w0[1] = __float2bfloat16(r00.y);
        w0[2] = __float2bfloat16(r00.z); w0[3] = __float2bfloat16(r00.w);
        w0[4] = __float2bfloat16(r01.x); w0[5] = __float2bfloat16(r01.y);
        w0[6] = __float2bfloat16(r01.z); w0[7] = __float2bfloat16(r01.w);
        w1[0] = __float2bfloat16(r10.x); w1[1] = __float2bfloat16(r10.y);
        w1[2] = __float2bfloat16(r10.z); w1[3] = __float2bfloat16(r10.w);
        w1[4] = __float2bfloat16(r11.x); w1[5] = __float2bfloat16(r11.y);
        w1[6] = __float2bfloat16(r11.z); w1[7] = __float2bfloat16(r11.w);
        *(bf16x8*)(la + wave * 1024 + lane * 16)        = *(const bf16x8*)w0;
        *(bf16x8*)(la + 4096 + wave * 1024 + lane * 16) = *(const bf16x8*)w1;
    };
    auto B_STAGE = [&](int t, int half) {
        char* const lb = bufB + half * 4096;
        const char* gb = (const char*)B
            + (brow0 + (size_t)(wave * 16 + lrow2)) * (KP * 2)
            + (size_t)t * 64 + sslot;
        gload16(gb, lb + wave * 1024);
    };

    const int rl   = lane & 15;
    const int koct = lane >> 4;
    const int rslot = ((koct ^ (rl & 3) ^ ((rl >> 2) & 3))) << 4;

    // prologue: buf0 and buf1 fully staged
    B_STAGE(0, 0);
    B_STAGE(1, 1);
    A_LOAD(0); A_WRITE(0);
    A_LOAD(1); A_WRITE(1);
    asm volatile("s_waitcnt vmcnt(0) lgkmcnt(0)" ::: "memory");
    __builtin_amdgcn_s_barrier();

    f32x4 acc[4][2] = {};

    for (int t = 0; t < NTV; ++t) {
        char* const aC = bufA + (t & 1) * 8192;
        char* const bC = bufB + (t & 1) * 4096;

        bf16x8 af[4], bfr[2];
        #pragma unroll
        for (int m = 0; m < 4; ++m) {
            const int r = wr * 64 + m * 16 + rl;
            af[m] = *(const bf16x8*)(aC + r * 64 + rslot);
        }
        #pragma unroll
        for (int n = 0; n < 2; ++n) {
            const int r = wc * 32 + n * 16 + rl;
            bfr[n] = *(const bf16x8*)(bC + r * 64 + rslot);
        }
        asm volatile("s_waitcnt lgkmcnt(0)" ::: "memory");   // also drains our ds_writes from t-1
        __builtin_amdgcn_sched_barrier(0);
        __builtin_amdgcn_s_barrier();   // all waves done reading buf t&1

        if (t + 2 < NTV) {
            B_STAGE(t + 2, t & 1);      // gload_lds into freed buf
            A_LOAD(t + 2);              // issue f32 loads early
        }

        __builtin_amdgcn_s_setprio(1);
        #pragma unroll
        for (int m = 0; m < 4; ++m)
            #pragma unroll
            for (int n = 0; n < 2; ++n)
                acc[m][n] = __builtin_amdgcn_mfma_f32_16x16x32_bf16(
                    bfr[n], af[m], acc[m][n], 0, 0, 0);
        __builtin_amdgcn_s_setprio(0);
        __builtin_amdgcn_sched_barrier(0);

        if (t + 2 < NTV) A_WRITE(t & 1);   // cvt (waits loads) + ds_write

        if (t < NTV - 1) __builtin_amdgcn_s_barrier();
    }

    const int obase = (int)arow0 + wr * 64 + rl;
    const int pbase = (int)brow0 + wc * 32 + koct * 4;
    #pragma unroll
    for (int m = 0; m < 4; ++m) {
        const int orow = obase + m * 16;
        #pragma unroll
        for (int n = 0; n < 2; ++n) {
            const int p = pbase + n * 16;
            alignas(8) __hip_bfloat16 t4[4];
            t4[0] = __float2bfloat16(acc[m][n][0]);
            t4[1] = __float2bfloat16(acc[m][n][1]);
            t4[2] = __float2bfloat16(acc[m][n][2]);
            t4[3] = __float2bfloat16(acc[m][n][3]);
            *(uint2*)(V + (size_t)orow * KST + p) = *(const uint2*)t4;
        }
    }
}

// ---------------------------------------------------------------------------
// Kernel 5 (R14/R20 proven, byte-identical): main GEMM 128x128, K=320.
// ---------------------------------------------------------------------------
__global__ __launch_bounds__(512, 4) void gemm_bt(
    const __hip_bfloat16* __restrict__ A,   // X: (N_ROWS, KST)
    const __hip_bfloat16* __restrict__ B,   // V: (OPAD, KST)
    float* __restrict__ C)
{
    __shared__ __align__(1024) char lds[65536];
    char* const bufA = lds;            // 2 x 16384 B
    char* const bufB = lds + 32768;    // 2 x 16384 B
    float* const s_c = (float*)lds;    // epilogue alias: [64][132] f32

    const int tid  = threadIdx.x;
    const int wave = tid >> 6;
    const int lane = tid & 63;

    const int bn = blockIdx.x;         // 22 col tiles
    const int bm = blockIdx.y;         // 250 row tiles
    const size_t arow0 = (size_t)bm * 128;
    const size_t brow0 = (size_t)bn * 128;

    const int wr = wave >> 2;
    const int wc = wave & 3;

    const int lrow  = lane >> 3;
    const int lslot = ((lane & 7) ^ (lrow & 7)) << 4;

    auto STAGE = [&](const char* gbase, size_t growbase, int t, char* lbase) {
        const char* g0 = gbase + (growbase + (size_t)(wave * 8 + lrow)) * (KST * 2)
                               + (size_t)t * 128 + lslot;
        gload16(g0,                          lbase + wave * 1024);
        gload16(g0 + (size_t)64 * (KST * 2), lbase + 8192 + wave * 1024);
    };

    const int rl   = lane & 15;
    const int koct = lane >> 4;
    const int sK0 = ((0 * 4 + koct) ^ (lane & 7)) << 4;
    const int sK1 = ((1 * 4 + koct) ^ (lane & 7)) << 4;

    STAGE((const char*)A, arow0, 0, bufA + 0);
    STAGE((const char*)B, brow0, 0, bufB + 0);
    STAGE((const char*)A, arow0, 1, bufA + 16384);
    STAGE((const char*)B, brow0, 1, bufB + 16384);
    asm volatile("s_waitcnt vmcnt(4)" ::: "memory");
    __builtin_amdgcn_s_barrier();

    f32x4 acc[4][2] = {};

    for (int t = 0; t < NT; ++t) {
        char* const aC = bufA + (t & 1) * 16384;
        char* const bC = bufB + (t & 1) * 16384;

        bf16x8 af[4][2], bfr[2][2];
        #pragma unroll
        for (int m = 0; m < 4; ++m) {
            const int r = wr * 64 + m * 16 + rl;
            af[m][0] = *(const bf16x8*)(aC + r * 128 + sK0);
            af[m][1] = *(const bf16x8*)(aC + r * 128 + sK1);
        }
        #pragma unroll
        for (int n = 0; n < 2; ++n) {
            const int r = wc * 32 + n * 16 + rl;
            bfr[n][0] = *(const bf16x8*)(bC + r * 128 + sK0);
            bfr[n][1] = *(const bf16x8*)(bC + r * 128 + sK1);
        }
        asm volatile("s_waitcnt lgkmcnt(0)" ::: "memory");
        __builtin_amdgcn_sched_barrier(0);
        __builtin_amdgcn_s_barrier();

        if (t + 2 < NT) {
            STAGE((const char*)A, arow0, t + 2, aC);
            STAGE((const char*)B, brow0, t + 2, bC);
        }

        __builtin_amdgcn_s_setprio(1);
        #pragma unroll
        for (int ks = 0; ks < 2; ++ks)
            #pragma unroll
            for (int m = 0; m < 4; ++m)
                #pragma unroll
                for (int n = 0; n < 2; ++n)
                    acc[m][n] = __builtin_amdgcn_mfma_f32_16x16x32_bf16(
                        bfr[n][ks], af[m][ks], acc[m][n], 0, 0, 0);
        __builtin_amdgcn_s_setprio(0);
        __builtin_amdgcn_sched_barrier(0);

        if (t < NT - 2)       asm volatile("s_waitcnt vmcnt(4)" ::: "memory");
        else if (t == NT - 2) asm volatile("s_waitcnt vmcnt(0)" ::: "memory");
        if (t < NT - 1) __builtin_amdgcn_s_barrier();
    }

    #pragma unroll
    for (int h = 0; h < 2; ++h) {
        __syncthreads();
        if (wr == h) {
            #pragma unroll
            for (int m = 0; m < 4; ++m) {
                const int row_l = m * 16 + rl;
                #pragma unroll
                for (int n = 0; n < 2; ++n) {
                    const int col = wc * 32 + n * 16 + koct * 4;
                    *(f32x4*)&s_c[row_l * 132 + col] = acc[m][n];
                }
            }
        }
        __syncthreads();
        #pragma unroll
        for (int rr = 0; rr < 4; ++rr) {
            const int idx  = rr * 512 + tid;
            const int row  = idx >> 5;
            const int g4   = (idx & 31) * 4;
            if ((int)brow0 + g4 < OCOLS) {
                const f32x4 v = *(const f32x4*)&s_c[row * 132 + g4];
                __builtin_nontemporal_store(v,
                    (f32x4*)(C + (size_t)(arow0 + h * 64 + row) * OCOLS + brow0 + g4));
            }
        }
    }
}

// ---------------------------------------------------------------------------
extern "C" void kernel_launch(void* const* d_in, const int* in_sizes, int n_in,
                              void* d_out, int out_size, void* d_ws, size_t ws_size,
                              hipStream_t stream)
{
    const float* sk  = (const float*)d_in[0];   // (16,16,125,12)
    const float* ang = (const float*)d_in[1];   // (32000,25)
    const float* W   = (const float*)d_in[2];   // (12,720)
    const float* TP  = (const float*)d_in[3];   // (2704,2704)
    float* out = (float*)d_out;                 // (32000,2704)

    __hip_bfloat16* X  = (__hip_bfloat16*)d_ws;             // 20.5 MB
    __hip_bfloat16* Vb = X  + (size_t)N_ROWS * KST;         // 1.8 MB
    __hip_bfloat16* Gt = Vb + (size_t)OPAD * KST;           // 1.74 MB

    prepG<<<NB_G, 256, 0, stream>>>(W, Gt);

    fused_V_X<<<NBV + NB_X, 256, 0, stream>>>(TP, Gt, Vb, sk, ang, X);

    dim3 grid(OPAD / 128, N_ROWS / 128);   // (22, 250)
    gemm_bt<<<grid, 512, 0, stream>>>(X, Vb, out);
}

// Round 23
// 129.741 us; speedup vs baseline: 1.2556x; 1.2556x over previous
//
#include <hip/hip_runtime.h>
#include <hip/hip_bf16.h>

// Problem geometry
#define N_ROWS 32000   // Q_OUT*Q_IN*NUM_P
#define SB     12      // SCALAR_BASIS
#define FC     720     // FILTER_C
#define FD     2704    // FILTER_DIM
#define OCOLS  2704    // DIM_OUT*DIM_IN
#define OPAD   2816    // padded o (22*128)
#define ANGD   25
#define PDIM   300     // SB * ANGD
#define KST    320     // PDIM padded to 5*64 (main GEMM K)
#define NT     5       // main GEMM K tiles of 64
#define KP     2720    // FD padded to 85*32 (V-GEMM K)
#define NTV    85      // V-GEMM K tiles of 32
#define GPR    (KP/8)  // 340 groups per TPb row

// launch-1 block ranges (cvt_M + build_G)
#define NB_CVT 3740    // OPAD*GPR/256
#define NB_G   425     // KST*GPR/256
// launch-2 block ranges (gemm_V + build_X)
#define NBV    110     // 5 * 22 V-GEMM tiles
#define NB_X   5000    // N_ROWS*(KST/8)/256

typedef __attribute__((ext_vector_type(8))) short bf16x8;
typedef __attribute__((ext_vector_type(4))) float f32x4;

__device__ __forceinline__ void gload16(const void* g, void* l) {
    __builtin_amdgcn_global_load_lds(
        (const __attribute__((address_space(1))) void*)g,
        (__attribute__((address_space(3))) void*)l, 16, 0, 0);
}

__device__ __forceinline__ void decode_f(int f, int& c, int& j, int& a) {
    if (f < 144)       { c = f;                         j = 0;            a = 0;  }
    else if (f < 960)  { int t = f - 144;  c = 144 + t/3; j = t - (t/3)*3; a = 1;  }
    else if (f < 2000) { int t = f - 960;  c = 416 + t/5; j = t - (t/5)*5; a = 4;  }
    else if (f < 2560) { int t = f - 2000; c = 624 + t/7; j = t - (t/7)*7; a = 9;  }
    else               { int t = f - 2560; c = 704 + t/9; j = t - (t/9)*9; a = 16; }
}

// ---------------------------------------------------------------------------
// Launch 1: cvt_M + build_G merged (R20 bodies, byte-identical).
// ---------------------------------------------------------------------------
__global__ __launch_bounds__(256) void prep1(
    const float* __restrict__ TP,
    const float* __restrict__ W,
    __hip_bfloat16* __restrict__ TPb,
    __hip_bfloat16* __restrict__ Gt)
{
    const int b = blockIdx.x;
    if (b < NB_CVT) {
        const int g = b * 256 + threadIdx.x;
        if (g >= OPAD * GPR) return;
        const int o = g / GPR;
        const int k = (g - o * GPR) * 8;
        alignas(16) __hip_bfloat16 tmp[8];
        if (o < OCOLS && k + 8 <= FD) {
            const float4* p = (const float4*)(TP + (size_t)o * FD + k);
            float4 x0 = p[0], x1 = p[1];
            tmp[0] = __float2bfloat16(x0.x); tmp[1] = __float2bfloat16(x0.y);
            tmp[2] = __float2bfloat16(x0.z); tmp[3] = __float2bfloat16(x0.w);
            tmp[4] = __float2bfloat16(x1.x); tmp[5] = __float2bfloat16(x1.y);
            tmp[6] = __float2bfloat16(x1.z); tmp[7] = __float2bfloat16(x1.w);
        } else {
            #pragma unroll
            for (int u = 0; u < 8; ++u) {
                float v = (o < OCOLS && k + u < FD) ? TP[(size_t)o * FD + k + u] : 0.f;
                tmp[u] = __float2bfloat16(v);
            }
        }
        *(bf16x8*)(TPb + (size_t)o * KP + k) = *(const bf16x8*)tmp;
    } else {
        const int g = (b - NB_CVT) * 256 + threadIdx.x;
        if (g >= KST * GPR) return;
        const int p  = g / GPR;
        const int f0 = (g - p * GPR) * 8;
        const int s     = p / ANGD;
        const int alpha = p - s * ANGD;
        const float inv = 0.28867513459481288f;
        alignas(16) __hip_bfloat16 tmp[8];
        #pragma unroll
        for (int u = 0; u < 8; ++u) {
            const int f = f0 + u;
            float v = 0.f;
            if (p < PDIM && f < FD) {
                int c, j, a;
                decode_f(f, c, j, a);
                if (alpha == a + j) v = W[s * FC + c] * inv;
            }
            tmp[u] = __float2bfloat16(v);
        }
        *(bf16x8*)(Gt + (size_t)p * KP + f0) = *(const bf16x8*)tmp;
    }
}

// ---------------------------------------------------------------------------
// Launch 2: fused gemm_V (blocks [0,NBV), R14/R20 body with flattened grid)
// + build_X (blocks [NBV, NBV+NB_X), R20 body). gemm_V blocks first so the
// 110 long blocks occupy CUs while 5000 short build_X blocks stream through
// the remaining CUs concurrently (they are mutually independent).
// ---------------------------------------------------------------------------
__global__ __launch_bounds__(256, 4) void fused_V_X(
    const __hip_bfloat16* __restrict__ A,   // TPb: (OPAD, KP)
    const __hip_bfloat16* __restrict__ B,   // Gt:  (KST, KP)
    __hip_bfloat16* __restrict__ V,         // (OPAD, KST)
    const float* __restrict__ sk,
    const float* __restrict__ ang,
    __hip_bfloat16* __restrict__ X)
{
    __shared__ __align__(1024) char lds[24576];

    if (blockIdx.x >= NBV) {
        // ---- build_X branch (no LDS use) ----
        const int idx = (blockIdx.x - NBV) * 256 + threadIdx.x;
        if (idx >= N_ROWS * (KST / 8)) return;
        const int n  = idx / (KST / 8);
        const int p0 = (idx - n * (KST / 8)) * 8;
        const float* skn  = sk  + (size_t)n * SB;
        const float* angn = ang + (size_t)n * ANGD;
        alignas(16) __hip_bfloat16 tmp[8];
        #pragma unroll
        for (int u = 0; u < 8; ++u) {
            const int p = p0 + u;
            float v = 0.f;
            if (p < PDIM) {
                const int s = p / ANGD;
                const int a = p - s * ANGD;
                v = skn[s] * angn[a];
            }
            tmp[u] = __float2bfloat16(v);
        }
        *(bf16x8*)(X + (size_t)n * KST + p0) = *(const bf16x8*)tmp;
        return;
    }

    // ---- gemm_V branch (R20 body; bn = id%5, bm = id/5) ----
    char* const bufA = lds;
    char* const bufB = lds + 16384;

    const int tid  = threadIdx.x;
    const int wave = tid >> 6;
    const int lane = tid & 63;

    const int id = blockIdx.x;
    const int bn = id % 5;             // 5 col tiles (64 p each)
    const int bm = id / 5;             // 22 row tiles (128 o each)
    const size_t arow0 = (size_t)bm * 128;
    const size_t brow0 = (size_t)bn * 64;

    const int wr = wave >> 1;
    const int wc = wave & 1;

    const int lrow2 = lane >> 2;
    const int sslot = (((lane & 3) ^ (lrow2 & 3) ^ ((lane >> 4) & 3))) << 4;

    auto STAGE = [&](int t, int half) {
        char* const la = bufA + half * 8192;
        char* const lb = bufB + half * 4096;
        const char* ga = (const char*)A
            + (arow0 + (size_t)(wave * 16 + lrow2)) * (KP * 2)
            + (size_t)t * 64 + sslot;
        gload16(ga,                         la + wave * 1024);
        gload16(ga + (size_t)64 * (KP * 2), la + 4096 + wave * 1024);
        const char* gb = (const char*)B
            + (brow0 + (size_t)(wave * 16 + lrow2)) * (KP * 2)
            + (size_t)t * 64 + sslot;
        gload16(gb, lb + wave * 1024);
    };

    const int rl   = lane & 15;
    const int koct = lane >> 4;
    const int rslot = ((koct ^ (rl & 3) ^ ((rl >> 2) & 3))) << 4;

    STAGE(0, 0);
    STAGE(1, 1);
    asm volatile("s_waitcnt vmcnt(3)" ::: "memory");
    __builtin_amdgcn_s_barrier();

    f32x4 acc[4][2] = {};

    for (int t = 0; t < NTV; ++t) {
        char* const aC = bufA + (t & 1) * 8192;
        char* const bC = bufB + (t & 1) * 4096;

        bf16x8 af[4], bfr[2];
        #pragma unroll
        for (int m = 0; m < 4; ++m) {
            const int r = wr * 64 + m * 16 + rl;
            af[m] = *(const bf16x8*)(aC + r * 64 + rslot);
        }
        #pragma unroll
        for (int n = 0; n < 2; ++n) {
            const int r = wc * 32 + n * 16 + rl;
            bfr[n] = *(const bf16x8*)(bC + r * 64 + rslot);
        }
        asm volatile("s_waitcnt lgkmcnt(0)" ::: "memory");
        __builtin_amdgcn_sched_barrier(0);
        __builtin_amdgcn_s_barrier();

        if (t + 2 < NTV) STAGE(t + 2, t & 1);

        __builtin_amdgcn_s_setprio(1);
        #pragma unroll
        for (int m = 0; m < 4; ++m)
            #pragma unroll
            for (int n = 0; n < 2; ++n)
                acc[m][n] = __builtin_amdgcn_mfma_f32_16x16x32_bf16(
                    bfr[n], af[m], acc[m][n], 0, 0, 0);
        __builtin_amdgcn_s_setprio(0);
        __builtin_amdgcn_sched_barrier(0);

        if (t < NTV - 2)       asm volatile("s_waitcnt vmcnt(3)" ::: "memory");
        else if (t == NTV - 2) asm volatile("s_waitcnt vmcnt(0)" ::: "memory");
        if (t < NTV - 1) __builtin_amdgcn_s_barrier();
    }

    const int obase = (int)arow0 + wr * 64 + rl;
    const int pbase = (int)brow0 + wc * 32 + koct * 4;
    #pragma unroll
    for (int m = 0; m < 4; ++m) {
        const int orow = obase + m * 16;
        #pragma unroll
        for (int n = 0; n < 2; ++n) {
            const int p = pbase + n * 16;
            alignas(8) __hip_bfloat16 t4[4];
            t4[0] = __float2bfloat16(acc[m][n][0]);
            t4[1] = __float2bfloat16(acc[m][n][1]);
            t4[2] = __float2bfloat16(acc[m][n][2]);
            t4[3] = __float2bfloat16(acc[m][n][3]);
            *(uint2*)(V + (size_t)orow * KST + p) = *(const uint2*)t4;
        }
    }
}

// ---------------------------------------------------------------------------
// Kernel 5 (R14/R20 proven, byte-identical): main GEMM 128x128, K=320.
// ---------------------------------------------------------------------------
__global__ __launch_bounds__(512, 4) void gemm_bt(
    const __hip_bfloat16* __restrict__ A,   // X: (N_ROWS, KST)
    const __hip_bfloat16* __restrict__ B,   // V: (OPAD, KST)
    float* __restrict__ C)
{
    __shared__ __align__(1024) char lds[65536];
    char* const bufA = lds;            // 2 x 16384 B
    char* const bufB = lds + 32768;    // 2 x 16384 B
    float* const s_c = (float*)lds;    // epilogue alias: [64][132] f32

    const int tid  = threadIdx.x;
    const int wave = tid >> 6;
    const int lane = tid & 63;

    const int bn = blockIdx.x;         // 22 col tiles
    const int bm = blockIdx.y;         // 250 row tiles
    const size_t arow0 = (size_t)bm * 128;
    const size_t brow0 = (size_t)bn * 128;

    const int wr = wave >> 2;
    const int wc = wave & 3;

    const int lrow  = lane >> 3;
    const int lslot = ((lane & 7) ^ (lrow & 7)) << 4;

    auto STAGE = [&](const char* gbase, size_t growbase, int t, char* lbase) {
        const char* g0 = gbase + (growbase + (size_t)(wave * 8 + lrow)) * (KST * 2)
                               + (size_t)t * 128 + lslot;
        gload16(g0,                          lbase + wave * 1024);
        gload16(g0 + (size_t)64 * (KST * 2), lbase + 8192 + wave * 1024);
    };

    const int rl   = lane & 15;
    const int koct = lane >> 4;
    const int sK0 = ((0 * 4 + koct) ^ (lane & 7)) << 4;
    const int sK1 = ((1 * 4 + koct) ^ (lane & 7)) << 4;

    STAGE((const char*)A, arow0, 0, bufA + 0);
    STAGE((const char*)B, brow0, 0, bufB + 0);
    STAGE((const char*)A, arow0, 1, bufA + 16384);
    STAGE((const char*)B, brow0, 1, bufB + 16384);
    asm volatile("s_waitcnt vmcnt(4)" ::: "memory");
    __builtin_amdgcn_s_barrier();

    f32x4 acc[4][2] = {};

    for (int t = 0; t < NT; ++t) {
        char* const aC = bufA + (t & 1) * 16384;
        char* const bC = bufB + (t & 1) * 16384;

        bf16x8 af[4][2], bfr[2][2];
        #pragma unroll
        for (int m = 0; m < 4; ++m) {
            const int r = wr * 64 + m * 16 + rl;
            af[m][0] = *(const bf16x8*)(aC + r * 128 + sK0);
            af[m][1] = *(const bf16x8*)(aC + r * 128 + sK1);
        }
        #pragma unroll
        for (int n = 0; n < 2; ++n) {
            const int r = wc * 32 + n * 16 + rl;
            bfr[n][0] = *(const bf16x8*)(bC + r * 128 + sK0);
            bfr[n][1] = *(const bf16x8*)(bC + r * 128 + sK1);
        }
        asm volatile("s_waitcnt lgkmcnt(0)" ::: "memory");
        __builtin_amdgcn_sched_barrier(0);
        __builtin_amdgcn_s_barrier();

        if (t + 2 < NT) {
            STAGE((const char*)A, arow0, t + 2, aC);
            STAGE((const char*)B, brow0, t + 2, bC);
        }

        __builtin_amdgcn_s_setprio(1);
        #pragma unroll
        for (int ks = 0; ks < 2; ++ks)
            #pragma unroll
            for (int m = 0; m < 4; ++m)
                #pragma unroll
                for (int n = 0; n < 2; ++n)
                    acc[m][n] = __builtin_amdgcn_mfma_f32_16x16x32_bf16(
                        bfr[n][ks], af[m][ks], acc[m][n], 0, 0, 0);
        __builtin_amdgcn_s_setprio(0);
        __builtin_amdgcn_sched_barrier(0);

        if (t < NT - 2)       asm volatile("s_waitcnt vmcnt(4)" ::: "memory");
        else if (t == NT - 2) asm volatile("s_waitcnt vmcnt(0)" ::: "memory");
        if (t < NT - 1) __builtin_amdgcn_s_barrier();
    }

    #pragma unroll
    for (int h = 0; h < 2; ++h) {
        __syncthreads();
        if (wr == h) {
            #pragma unroll
            for (int m = 0; m < 4; ++m) {
                const int row_l = m * 16 + rl;
                #pragma unroll
                for (int n = 0; n < 2; ++n) {
                    const int col = wc * 32 + n * 16 + koct * 4;
                    *(f32x4*)&s_c[row_l * 132 + col] = acc[m][n];
                }
            }
        }
        __syncthreads();
        #pragma unroll
        for (int rr = 0; rr < 4; ++rr) {
            const int idx  = rr * 512 + tid;
            const int row  = idx >> 5;
            const int g4   = (idx & 31) * 4;
            if ((int)brow0 + g4 < OCOLS) {
                const f32x4 v = *(const f32x4*)&s_c[row * 132 + g4];
                __builtin_nontemporal_store(v,
                    (f32x4*)(C + (size_t)(arow0 + h * 64 + row) * OCOLS + brow0 + g4));
            }
        }
    }
}

// ---------------------------------------------------------------------------
extern "C" void kernel_launch(void* const* d_in, const int* in_sizes, int n_in,
                              void* d_out, int out_size, void* d_ws, size_t ws_size,
                              hipStream_t stream)
{
    const float* sk  = (const float*)d_in[0];   // (16,16,125,12)
    const float* ang = (const float*)d_in[1];   // (32000,25)
    const float* W   = (const float*)d_in[2];   // (12,720)
    const float* TP  = (const float*)d_in[3];   // (2704,2704)
    float* out = (float*)d_out;                 // (32000,2704)

    __hip_bfloat16* X   = (__hip_bfloat16*)d_ws;              // 20.5 MB
    __hip_bfloat16* Vb  = X   + (size_t)N_ROWS * KST;         // 1.8 MB
    __hip_bfloat16* TPb = Vb  + (size_t)OPAD * KST;           // 15.3 MB
    __hip_bfloat16* Gt  = TPb + (size_t)OPAD * KP;            // 1.74 MB

    prep1<<<NB_CVT + NB_G, 256, 0, stream>>>(TP, W, TPb, Gt);

    fused_V_X<<<NBV + NB_X, 256, 0, stream>>>(TPb, Gt, Vb, sk, ang, X);

    dim3 grid(OPAD / 128, N_ROWS / 128);   // (22, 250)
    gemm_bt<<<grid, 512, 0, stream>>>(X, Vb, out);
}